// Round 5
// baseline (11066.370 us; speedup 1.0000x reference)
//
#include <hip/hip_runtime.h>
#include <math.h>

// Deep ESN, fp32, persistent wavefront-pipelined kernel, round 5.
// vs R2/R4: (a) barrier = inv-at-arrive: every block runs the agent acquire
// fence (waitcnt + buffer_inv sc1) BEFORE its arrive-add, overlapped with
// the poll window; no leader election, no done-flags (R4's post-release
// leader chain cost ~4us/tick). All invs complete before global release by
// construction. State loads are plain cached float4; stores sc1 write-through.
// (b) reduce-scatter reduction: 15 LDS-pipe shfl/wave (was 160), DPP for the
// first stage; every lane ends with exactly 1 output (A=kq).
// (c) float2 ext-vector accumulators -> v_pk_fma_f32 (packed fp32 rate).

#define TT    512
#define RDIM  1024
#define EDIM  256
#define NL    4
#define BB    32
#define NBLK  512          // 128 blocks per layer
#define JW    8            // output columns per block
#define HDIM  (RDIM * NL)  // 4096
#define NPAN  4            // 4 panels of 8 batch rows
#define CSTRIDE 32         // dwords between counter words (128B lines)

#define S_ELEMS   (2 * NL * NPAN * RDIM * 8)   // 2 parities, 1MB
#define FIN_ELEMS (BB * HDIM)

typedef float vf2 __attribute__((ext_vector_type(2)));

__device__ __forceinline__ float dpp_xor1(float x) {   // lane ^ 1 (quad_perm 1,0,3,2)
    return __int_as_float(__builtin_amdgcn_mov_dpp(__float_as_int(x), 0xB1, 0xF, 0xF, true));
}
__device__ __forceinline__ float dpp_xor2(float x) {   // lane ^ 2 (quad_perm 2,3,0,1)
    return __int_as_float(__builtin_amdgcn_mov_dpp(__float_as_int(x), 0x4E, 0xF, 0xF, true));
}

// ---------------------------------------------------------------- gather ----
// xe[t][panel][k][8b] : panel layout matching reservoir reads
__global__ void gather_kernel(const int* __restrict__ x,
                              const float* __restrict__ embed,
                              float* __restrict__ xe)
{
    __shared__ int   ids[BB];
    __shared__ float sh[BB * (EDIM + 1)];
    const int t = blockIdx.x, tid = threadIdx.x;
    if (tid < BB) ids[tid] = x[tid * TT + t];
    __syncthreads();
    for (int r = 0; r < BB; ++r)
        sh[r * (EDIM + 1) + tid] = embed[ids[r] * EDIM + tid];
    __syncthreads();
    for (int i = tid; i < NPAN * EDIM * 8; i += 256) {
        int p = i >> 11, k = (i >> 3) & (EDIM - 1), bo = i & 7;
        xe[(size_t)t * (NPAN * EDIM * 8) + i] = sh[(p * 8 + bo) * (EDIM + 1) + k];
    }
}

// ------------------------------------------------------------- reservoir ----
__global__ __launch_bounds__(256, 2) void reservoir_kernel(
    const float* __restrict__ Win0, const float* __restrict__ WinR,
    const float* __restrict__ Rst,  const float* __restrict__ xe,
    float* __restrict__ S, float* __restrict__ Fin, unsigned* __restrict__ cnt)
{
    __shared__ float Wlds[2048 * JW];       // 64 KB, row k = 8 floats (j0..j0+7)
    const int tid   = threadIdx.x;
    const int blk   = blockIdx.x;
    const int layer = blk >> 7;
    const int j0    = (blk & 127) * JW;
    const int Kin   = (layer == 0) ? EDIM : RDIM;

    for (int idx = tid; idx < (RDIM + Kin) * JW; idx += 256) {
        int k = idx >> 3, j = idx & 7;
        float wv;
        if (k < RDIM) wv = Rst[((size_t)layer * RDIM + k) * RDIM + j0 + j];
        else {
            int k2 = k - RDIM;
            wv = (layer == 0) ? Win0[(size_t)k2 * RDIM + j0 + j]
                              : WinR[((size_t)(layer - 1) * RDIM + k2) * RDIM + j0 + j];
        }
        Wlds[idx] = wv;
    }
    __syncthreads();

    const int w   = tid >> 6;   // wave -> panel (8 batch rows)
    const int lam = tid & 63;
    const int kq  = lam >> 1;   // 32-way k split within wave
    const int bh  = lam & 1;    // which float4 of the 8-wide batch row
    const int bh4 = bh * 4;

    // epilogue ownership after reduce-scatter: lane holds A = kq
    // -> i = kq>>3 (v component), local col = (kq&7)^bh4 (DPP col permute)
    const int ei   = kq >> 3;
    const int ecol = (kq & 7) ^ bh4;
    const int eoff = ecol * 8 + bh4 + ei;          // within-panel float offset
    const int eb   = w * 8 + bh4 + ei;             // global batch row

    for (int tick = 0; tick < TT + NL - 1; ++tick) {
        const int t = tick - layer;
        if (t >= 0 && t < TT) {
            const int cur = tick & 1, prv = (tick - 1) & 1;
            const float4* ownp = (const float4*)(S + (((size_t)(prv * NL + layer)) * NPAN + w) * RDIM * 8);
            const float4* inpp = (layer == 0)
                ? (const float4*)(xe + ((size_t)t * NPAN + w) * (EDIM * 8))
                : (const float4*)(S + (((size_t)(prv * NL + layer - 1)) * NPAN + w) * RDIM * 8);

            vf2 acc[4][4];
            #pragma unroll
            for (int i = 0; i < 4; ++i)
                #pragma unroll
                for (int jp = 0; jp < 4; ++jp) acc[i][jp] = (vf2)(0.f);

            // ---- own state @ R_stack ----
            #pragma unroll 8
            for (int kk = 0; kk < RDIM / 32; ++kk) {
                float4 v  = ownp[(size_t)kk * 64 + lam];              // 1KB/wave
                float4 wo = *(const float4*)&Wlds[(kk * 32 + kq) * 8 + bh4];
                vf2 w0 = {wo.x, wo.y}, w1 = {wo.z, wo.w};
                vf2 w2 = {dpp_xor1(wo.x), dpp_xor1(wo.y)};
                vf2 w3 = {dpp_xor1(wo.z), dpp_xor1(wo.w)};
                const float vv[4] = {v.x, v.y, v.z, v.w};
                #pragma unroll
                for (int i = 0; i < 4; ++i) {
                    vf2 s = {vv[i], vv[i]};
                    acc[i][0] += s * w0; acc[i][1] += s * w1;
                    acc[i][2] += s * w2; acc[i][3] += s * w3;
                }
            }
            // ---- layer input @ Win ----
            #pragma unroll 8
            for (int kk = 0; kk < Kin / 32; ++kk) {
                float4 v  = inpp[(size_t)kk * 64 + lam];
                float4 wo = *(const float4*)&Wlds[(RDIM + kk * 32 + kq) * 8 + bh4];
                vf2 w0 = {wo.x, wo.y}, w1 = {wo.z, wo.w};
                vf2 w2 = {dpp_xor1(wo.x), dpp_xor1(wo.y)};
                vf2 w3 = {dpp_xor1(wo.z), dpp_xor1(wo.w)};
                const float vv[4] = {v.x, v.y, v.z, v.w};
                #pragma unroll
                for (int i = 0; i < 4; ++i) {
                    vf2 s = {vv[i], vv[i]};
                    acc[i][0] += s * w0; acc[i][1] += s * w1;
                    acc[i][2] += s * w2; acc[i][3] += s * w3;
                }
            }

            // ---- reduce-scatter over kq (5 stages, values halve each stage) ----
            // acc index A = (i<<3) | j ; lane ends owning A == kq.
            float r32[32];
            #pragma unroll
            for (int i = 0; i < 4; ++i)
                #pragma unroll
                for (int jp = 0; jp < 4; ++jp) {
                    r32[(i << 3) | (jp << 1)]     = acc[i][jp].x;
                    r32[(i << 3) | (jp << 1) | 1] = acc[i][jp].y;
                }
            float r16[16], r8[8], r4[4], r2[2], rfin;
            {   // stage 0: kq^1 == lam^2 -> DPP
                const bool myb = (kq & 1);
                #pragma unroll
                for (int m = 0; m < 16; ++m) {
                    float send = myb ? r32[2 * m] : r32[2 * m + 1];
                    float keep = myb ? r32[2 * m + 1] : r32[2 * m];
                    r16[m] = keep + dpp_xor2(send);
                }
            }
            {   // stage 1: kq^2 == lam^4
                const bool myb = (kq >> 1) & 1;
                #pragma unroll
                for (int m = 0; m < 8; ++m) {
                    float send = myb ? r16[2 * m] : r16[2 * m + 1];
                    float keep = myb ? r16[2 * m + 1] : r16[2 * m];
                    r8[m] = keep + __shfl_xor(send, 4, 64);
                }
            }
            {   // stage 2: kq^4 == lam^8
                const bool myb = (kq >> 2) & 1;
                #pragma unroll
                for (int m = 0; m < 4; ++m) {
                    float send = myb ? r8[2 * m] : r8[2 * m + 1];
                    float keep = myb ? r8[2 * m + 1] : r8[2 * m];
                    r4[m] = keep + __shfl_xor(send, 8, 64);
                }
            }
            {   // stage 3: kq^8 == lam^16
                const bool myb = (kq >> 3) & 1;
                #pragma unroll
                for (int m = 0; m < 2; ++m) {
                    float send = myb ? r4[2 * m] : r4[2 * m + 1];
                    float keep = myb ? r4[2 * m + 1] : r4[2 * m];
                    r2[m] = keep + __shfl_xor(send, 16, 64);
                }
            }
            {   // stage 4: kq^16 == lam^32
                const bool myb = (kq >> 4) & 1;
                float send = myb ? r2[0] : r2[1];
                float keep = myb ? r2[1] : r2[0];
                rfin = keep + __shfl_xor(send, 32, 64);
            }

            const float o = tanhf(rfin);
            float* dst = S + (((size_t)(cur * NL + layer)) * NPAN + w) * RDIM * 8
                           + (size_t)j0 * 8 + eoff;
            __hip_atomic_store(dst, o, __ATOMIC_RELAXED, __HIP_MEMORY_SCOPE_AGENT);
            if (t == TT - 1)
                Fin[(size_t)eb * HDIM + layer * RDIM + j0 + ecol] = o;
        }
        // ---- grid barrier: inv-at-arrive (pre-release), relaxed poll ----
        __syncthreads();                          // all waves' stores drained
        if (tid < 64) {
            // acquire fence now = s_waitcnt + buffer_inv sc1 (L1+L2), BEFORE
            // arrive -> all invs complete before global release; stale lines
            // (same-parity, 2 ticks old) are gone before anyone reads.
            __builtin_amdgcn_fence(__ATOMIC_ACQUIRE, "agent");
            if (lam == 0)
                __hip_atomic_fetch_add(&cnt[(blk & 15) * CSTRIDE], 1u,
                                       __ATOMIC_RELAXED, __HIP_MEMORY_SCOPE_AGENT);
            const unsigned want = (unsigned)(tick + 1) * (unsigned)NBLK;
            int guard = 0;
            for (;;) {
                unsigned v = __hip_atomic_load(&cnt[(lam & 15) * CSTRIDE],
                                               __ATOMIC_RELAXED, __HIP_MEMORY_SCOPE_AGENT);
                #pragma unroll
                for (int m = 1; m <= 8; m <<= 1) v += __shfl_xor(v, m, 64);
                if (v >= want) break;
                __builtin_amdgcn_s_sleep(1);
                if (++guard > (1 << 14)) break;   // safety valve
            }
        }
        __syncthreads();
    }
}

// ------------------------------------------------------------- layernorm ----
__global__ void ln_kernel(const float* __restrict__ Fin,
                          const float* __restrict__ gamma,
                          const float* __restrict__ beta,
                          float* __restrict__ out)
{
    const int r = blockIdx.x, tid = threadIdx.x;
    const float* row = Fin + (size_t)r * HDIM;
    float s = 0.f, s2 = 0.f;
    for (int i = tid; i < HDIM; i += 256) { float v = row[i]; s += v; s2 += v * v; }
    for (int off = 32; off; off >>= 1) {
        s  += __shfl_down(s,  off, 64);
        s2 += __shfl_down(s2, off, 64);
    }
    __shared__ float rs[4], rs2[4];
    __shared__ float mu_s, rstd_s;
    if ((tid & 63) == 0) { rs[tid >> 6] = s; rs2[tid >> 6] = s2; }
    __syncthreads();
    if (tid == 0) {
        float S1 = rs[0] + rs[1] + rs[2] + rs[3];
        float S2 = rs2[0] + rs2[1] + rs2[2] + rs2[3];
        float mu = S1 / (float)HDIM;
        float var = S2 / (float)HDIM - mu * mu;
        mu_s = mu; rstd_s = rsqrtf(var + 1e-5f);
    }
    __syncthreads();
    float mu = mu_s, rstd = rstd_s;
    for (int i = tid; i < HDIM; i += 256)
        out[(size_t)r * HDIM + i] = (row[i] - mu) * rstd * gamma[i] + beta[i];
}

// ----------------------------------------------------------------- launch ---
extern "C" void kernel_launch(void* const* d_in, const int* in_sizes, int n_in,
                              void* d_out, int out_size, void* d_ws, size_t ws_size,
                              hipStream_t stream)
{
    const int*   x     = (const int*)d_in[0];
    const float* embed = (const float*)d_in[1];
    const float* Win0  = (const float*)d_in[2];
    const float* WinR  = (const float*)d_in[3];
    const float* Rst   = (const float*)d_in[4];
    const float* gamma = (const float*)d_in[5];
    const float* beta  = (const float*)d_in[6];
    float* out = (float*)d_out;

    char* ws = (char*)d_ws;
    unsigned* cnt = (unsigned*)ws;                                   // 16 lines
    float* S   = (float*)(ws + 8192);                                // 1MB
    float* Fin = S + S_ELEMS;                                        // 0.5MB
    float* xe  = Fin + FIN_ELEMS;                                    // 16.8MB

    hipMemsetAsync(ws, 0, 8192 + (size_t)S_ELEMS * 4, stream);       // cnt + states
    gather_kernel   <<<TT,   256, 0, stream>>>(x, embed, xe);
    reservoir_kernel<<<NBLK, 256, 0, stream>>>(Win0, WinR, Rst, xe, S, Fin, cnt);
    ln_kernel       <<<BB,   256, 0, stream>>>(Fin, gamma, beta, out);
}

// Round 6
// 8447.697 us; speedup vs baseline: 1.3100x; 1.3100x over previous
//
#include <hip/hip_runtime.h>
#include <math.h>

// Deep ESN, fp32, persistent wavefront-pipelined kernel, round 6.
// Sync model = R2 exactly (the only correct-and-fast one measured): sc1
// relaxed agent atomics for ALL state traffic, relaxed barrier, ZERO cache
// fences (R3/R4/R5 proved every buffer_inv scheme loses).
// Change vs R2: halve MALL traffic (the 10.7 TB/s binding limit) by halving
// the consumer count: JW=16 (64 blocks/layer), 16 cols/lane, 128KB weight
// LDS, 1 block/CU. Compute uses R5's wins: v_pk_fma_f32, DPP weight
// sharing, DPP+shfl reduce-scatter.

#define TT    512
#define RDIM  1024
#define EDIM  256
#define NL    4
#define BB    32
#define NBLK  256          // 64 blocks per layer
#define JW    16           // output columns per block
#define HDIM  (RDIM * NL)  // 4096
#define NPAN  4            // 4 panels of 8 batch rows
#define CSTRIDE 32         // dwords between counter words (128B lines)

#define S_ELEMS   (2 * NL * NPAN * RDIM * 8)   // 2 parities, 1MB
#define FIN_ELEMS (BB * HDIM)

typedef float vf2 __attribute__((ext_vector_type(2)));
typedef unsigned long long ull;

__device__ __forceinline__ float2 aload2(const ull* p) {   // 8B sc1 load
    ull u = __hip_atomic_load(p, __ATOMIC_RELAXED, __HIP_MEMORY_SCOPE_AGENT);
    union { ull u; float2 f; } c; c.u = u; return c.f;
}
__device__ __forceinline__ float dpp_xor1(float x) {   // lane ^ 1
    return __int_as_float(__builtin_amdgcn_mov_dpp(__float_as_int(x), 0xB1, 0xF, 0xF, true));
}
__device__ __forceinline__ float dpp_xor2(float x) {   // lane ^ 2
    return __int_as_float(__builtin_amdgcn_mov_dpp(__float_as_int(x), 0x4E, 0xF, 0xF, true));
}

// ---------------------------------------------------------------- gather ----
// xe[t][panel][k][8b] : panel layout matching reservoir reads
__global__ void gather_kernel(const int* __restrict__ x,
                              const float* __restrict__ embed,
                              float* __restrict__ xe)
{
    __shared__ int   ids[BB];
    __shared__ float sh[BB * (EDIM + 1)];
    const int t = blockIdx.x, tid = threadIdx.x;
    if (tid < BB) ids[tid] = x[tid * TT + t];
    __syncthreads();
    for (int r = 0; r < BB; ++r)
        sh[r * (EDIM + 1) + tid] = embed[ids[r] * EDIM + tid];
    __syncthreads();
    for (int i = tid; i < NPAN * EDIM * 8; i += 256) {
        int p = i >> 11, k = (i >> 3) & (EDIM - 1), bo = i & 7;
        xe[(size_t)t * (NPAN * EDIM * 8) + i] = sh[(p * 8 + bo) * (EDIM + 1) + k];
    }
}

// ------------------------------------------------------------- reservoir ----
__global__ __launch_bounds__(256, 1) void reservoir_kernel(
    const float* __restrict__ Win0, const float* __restrict__ WinR,
    const float* __restrict__ Rst,  const float* __restrict__ xe,
    float* __restrict__ S, float* __restrict__ Fin, unsigned* __restrict__ cnt)
{
    __shared__ float Wlds[2048 * JW];       // 128 KB, row k = 16 floats
    const int tid   = threadIdx.x;
    const int blk   = blockIdx.x;
    const int layer = blk >> 6;
    const int j0    = (blk & 63) * JW;
    const int Kin   = (layer == 0) ? EDIM : RDIM;

    // rows [0,1024) = R_stack col-slice, rows [1024,1024+Kin) = Win col-slice
    for (int idx = tid; idx < (RDIM + Kin) * JW; idx += 256) {
        int k = idx >> 4, j = idx & 15;
        float wv;
        if (k < RDIM) wv = Rst[((size_t)layer * RDIM + k) * RDIM + j0 + j];
        else {
            int k2 = k - RDIM;
            wv = (layer == 0) ? Win0[(size_t)k2 * RDIM + j0 + j]
                              : WinR[((size_t)(layer - 1) * RDIM + k2) * RDIM + j0 + j];
        }
        Wlds[idx] = wv;
    }
    __syncthreads();

    const int w   = tid >> 6;   // wave -> panel (8 batch rows)
    const int lam = tid & 63;
    const int kq  = lam >> 1;   // 32-way k split within wave
    const int bh  = lam & 1;    // which float4 of the 8-wide batch row
    const int bh4 = bh * 4;

    for (int tick = 0; tick < TT + NL - 1; ++tick) {
        const int t = tick - layer;
        if (t >= 0 && t < TT) {
            const int cur = tick & 1, prv = (tick - 1) & 1;
            const ull* ownp = (const ull*)(S + (((size_t)(prv * NL + layer)) * NPAN + w) * RDIM * 8);
            const ull* inps = (const ull*)(S + (((size_t)(prv * NL + layer - 1)) * NPAN + w) * RDIM * 8);
            const float4* inpx = (const float4*)(xe + ((size_t)t * NPAN + w) * (EDIM * 8));

            // acc[i][jp]: i = v-component (batch sub-row), jp pairs of acc-col cc
            // cc<8: own-loaded weight cols (logical bh*8 + cc)
            // cc>=8: DPP partner cols  (logical (1-bh)*8 + (cc-8))
            vf2 acc[4][8];
            #pragma unroll
            for (int i = 0; i < 4; ++i)
                #pragma unroll
                for (int jp = 0; jp < 8; ++jp) acc[i][jp] = (vf2)(0.f);

            // ---- own state @ R_stack (sc1 loads: coherent, no fences) ----
            #pragma unroll 8
            for (int kk = 0; kk < RDIM / 32; ++kk) {
                const ull* p = ownp + (size_t)kk * 128 + lam * 2;   // 1KB/wave
                float2 v0 = aload2(p), v1 = aload2(p + 1);
                const int k = kk * 32 + kq;
                float4 wo0 = *(const float4*)&Wlds[k * JW + bh * 8];
                float4 wo1 = *(const float4*)&Wlds[k * JW + bh * 8 + 4];
                vf2 wv[8];
                wv[0] = (vf2){wo0.x, wo0.y}; wv[1] = (vf2){wo0.z, wo0.w};
                wv[2] = (vf2){wo1.x, wo1.y}; wv[3] = (vf2){wo1.z, wo1.w};
                wv[4] = (vf2){dpp_xor1(wo0.x), dpp_xor1(wo0.y)};
                wv[5] = (vf2){dpp_xor1(wo0.z), dpp_xor1(wo0.w)};
                wv[6] = (vf2){dpp_xor1(wo1.x), dpp_xor1(wo1.y)};
                wv[7] = (vf2){dpp_xor1(wo1.z), dpp_xor1(wo1.w)};
                const float vv[4] = {v0.x, v0.y, v1.x, v1.y};
                #pragma unroll
                for (int i = 0; i < 4; ++i) {
                    vf2 s = {vv[i], vv[i]};
                    #pragma unroll
                    for (int jp = 0; jp < 8; ++jp) acc[i][jp] += s * wv[jp];
                }
            }
            // ---- layer input @ Win ----
            #pragma unroll 8
            for (int kk = 0; kk < Kin / 32; ++kk) {
                float2 v0, v1;
                if (layer == 0) {                       // xe: read-only, cached
                    float4 v = inpx[(size_t)kk * 64 + lam];
                    v0 = (float2){v.x, v.y}; v1 = (float2){v.z, v.w};
                } else {                                // state: sc1
                    const ull* p = inps + (size_t)kk * 128 + lam * 2;
                    v0 = aload2(p); v1 = aload2(p + 1);
                }
                const int k = RDIM + kk * 32 + kq;
                float4 wo0 = *(const float4*)&Wlds[k * JW + bh * 8];
                float4 wo1 = *(const float4*)&Wlds[k * JW + bh * 8 + 4];
                vf2 wv[8];
                wv[0] = (vf2){wo0.x, wo0.y}; wv[1] = (vf2){wo0.z, wo0.w};
                wv[2] = (vf2){wo1.x, wo1.y}; wv[3] = (vf2){wo1.z, wo1.w};
                wv[4] = (vf2){dpp_xor1(wo0.x), dpp_xor1(wo0.y)};
                wv[5] = (vf2){dpp_xor1(wo0.z), dpp_xor1(wo0.w)};
                wv[6] = (vf2){dpp_xor1(wo1.x), dpp_xor1(wo1.y)};
                wv[7] = (vf2){dpp_xor1(wo1.z), dpp_xor1(wo1.w)};
                const float vv[4] = {v0.x, v0.y, v1.x, v1.y};
                #pragma unroll
                for (int i = 0; i < 4; ++i) {
                    vf2 s = {vv[i], vv[i]};
                    #pragma unroll
                    for (int jp = 0; jp < 8; ++jp) acc[i][jp] += s * wv[jp];
                }
            }

            // ---- reduce-scatter over kq: 64 accs -> 2 finals per lane ----
            // A = (i<<4) | cc ; stage s exchanges kq-bit s (lane xor 2<<s);
            // lane ends owning A = kq and A = kq+32.
            float r64v[64];
            #pragma unroll
            for (int i = 0; i < 4; ++i)
                #pragma unroll
                for (int jp = 0; jp < 8; ++jp) {
                    r64v[(i << 4) | (jp << 1)]     = acc[i][jp].x;
                    r64v[(i << 4) | (jp << 1) | 1] = acc[i][jp].y;
                }
            float r32v[32], r16v[16], r8v[8], r4v[4], rfin[2];
            {   const bool myb = kq & 1;                 // stage 0: DPP xor2
                #pragma unroll
                for (int m = 0; m < 32; ++m) {
                    float a = r64v[2 * m], b = r64v[2 * m + 1];
                    float send = myb ? a : b, keep = myb ? b : a;
                    r32v[m] = keep + dpp_xor2(send);
                }
            }
            {   const bool myb = (kq >> 1) & 1;          // stage 1: xor 4
                #pragma unroll
                for (int m = 0; m < 16; ++m) {
                    float a = r32v[2 * m], b = r32v[2 * m + 1];
                    float send = myb ? a : b, keep = myb ? b : a;
                    r16v[m] = keep + __shfl_xor(send, 4, 64);
                }
            }
            {   const bool myb = (kq >> 2) & 1;          // stage 2: xor 8
                #pragma unroll
                for (int m = 0; m < 8; ++m) {
                    float a = r16v[2 * m], b = r16v[2 * m + 1];
                    float send = myb ? a : b, keep = myb ? b : a;
                    r8v[m] = keep + __shfl_xor(send, 8, 64);
                }
            }
            {   const bool myb = (kq >> 3) & 1;          // stage 3: xor 16
                #pragma unroll
                for (int m = 0; m < 4; ++m) {
                    float a = r8v[2 * m], b = r8v[2 * m + 1];
                    float send = myb ? a : b, keep = myb ? b : a;
                    r4v[m] = keep + __shfl_xor(send, 16, 64);
                }
            }
            {   const bool myb = (kq >> 4) & 1;          // stage 4: xor 32
                #pragma unroll
                for (int m = 0; m < 2; ++m) {
                    float a = r4v[2 * m], b = r4v[2 * m + 1];
                    float send = myb ? a : b, keep = myb ? b : a;
                    rfin[m] = keep + __shfl_xor(send, 32, 64);
                }
            }

            // ---- epilogue: 2 outputs per lane ----
            const int i0 = kq >> 4;                 // 0..1
            const int cc = kq & 15;
            const int j  = (cc & 7) + 8 * (bh ^ (cc >> 3));   // logical col
            float* sbase = S + (((size_t)(cur * NL + layer)) * NPAN + w) * RDIM * 8
                             + (size_t)(j0 + j) * 8;
            #pragma unroll
            for (int m = 0; m < 2; ++m) {
                const int bi = bh4 + i0 + 2 * m;    // slot within panel's 8
                const float o = tanhf(rfin[m]);
                __hip_atomic_store(sbase + bi, o, __ATOMIC_RELAXED, __HIP_MEMORY_SCOPE_AGENT);
                if (t == TT - 1)
                    Fin[(size_t)(w * 8 + bi) * HDIM + layer * RDIM + j0 + j] = o;
            }
        }
        // ---- grid barrier: relaxed agent atomics only (R2 model) ----
        __syncthreads();                          // drains all waves' stores
        if (tid == 0)
            __hip_atomic_fetch_add(&cnt[(blk & 15) * CSTRIDE], 1u,
                                   __ATOMIC_RELAXED, __HIP_MEMORY_SCOPE_AGENT);
        if (tid < 64) {                           // wave 0 polls 16 counters
            const unsigned want = (unsigned)(tick + 1) * (unsigned)NBLK;
            int guard = 0;
            for (;;) {
                unsigned v = __hip_atomic_load(&cnt[(lam & 15) * CSTRIDE],
                                               __ATOMIC_RELAXED, __HIP_MEMORY_SCOPE_AGENT);
                #pragma unroll
                for (int m = 1; m <= 8; m <<= 1) v += __shfl_xor(v, m, 64);
                if (v >= want) break;
                __builtin_amdgcn_s_sleep(1);
                if (++guard > (1 << 14)) break;   // safety valve
            }
        }
        __syncthreads();
    }
}

// ------------------------------------------------------------- layernorm ----
__global__ void ln_kernel(const float* __restrict__ Fin,
                          const float* __restrict__ gamma,
                          const float* __restrict__ beta,
                          float* __restrict__ out)
{
    const int r = blockIdx.x, tid = threadIdx.x;
    const float* row = Fin + (size_t)r * HDIM;
    float s = 0.f, s2 = 0.f;
    for (int i = tid; i < HDIM; i += 256) { float v = row[i]; s += v; s2 += v * v; }
    for (int off = 32; off; off >>= 1) {
        s  += __shfl_down(s,  off, 64);
        s2 += __shfl_down(s2, off, 64);
    }
    __shared__ float rs[4], rs2[4];
    __shared__ float mu_s, rstd_s;
    if ((tid & 63) == 0) { rs[tid >> 6] = s; rs2[tid >> 6] = s2; }
    __syncthreads();
    if (tid == 0) {
        float S1 = rs[0] + rs[1] + rs[2] + rs[3];
        float S2 = rs2[0] + rs2[1] + rs2[2] + rs2[3];
        float mu = S1 / (float)HDIM;
        float var = S2 / (float)HDIM - mu * mu;
        mu_s = mu; rstd_s = rsqrtf(var + 1e-5f);
    }
    __syncthreads();
    float mu = mu_s, rstd = rstd_s;
    for (int i = tid; i < HDIM; i += 256)
        out[(size_t)r * HDIM + i] = (row[i] - mu) * rstd * gamma[i] + beta[i];
}

// ----------------------------------------------------------------- launch ---
extern "C" void kernel_launch(void* const* d_in, const int* in_sizes, int n_in,
                              void* d_out, int out_size, void* d_ws, size_t ws_size,
                              hipStream_t stream)
{
    const int*   x     = (const int*)d_in[0];
    const float* embed = (const float*)d_in[1];
    const float* Win0  = (const float*)d_in[2];
    const float* WinR  = (const float*)d_in[3];
    const float* Rst   = (const float*)d_in[4];
    const float* gamma = (const float*)d_in[5];
    const float* beta  = (const float*)d_in[6];
    float* out = (float*)d_out;

    char* ws = (char*)d_ws;
    unsigned* cnt = (unsigned*)ws;                                   // 16 lines
    float* S   = (float*)(ws + 8192);                                // 1MB
    float* Fin = S + S_ELEMS;                                        // 0.5MB
    float* xe  = Fin + FIN_ELEMS;                                    // 16.8MB

    hipMemsetAsync(ws, 0, 8192 + (size_t)S_ELEMS * 4, stream);       // cnt + states
    gather_kernel   <<<TT,   256, 0, stream>>>(x, embed, xe);
    reservoir_kernel<<<NBLK, 256, 0, stream>>>(Win0, WinR, Rst, xe, S, Fin, cnt);
    ln_kernel       <<<BB,   256, 0, stream>>>(Fin, gamma, beta, out);
}

// Round 7
// 7877.891 us; speedup vs baseline: 1.4047x; 1.0723x over previous
//
#include <hip/hip_runtime.h>
#include <math.h>

// Deep ESN, fp32, persistent wavefront-pipelined kernel, round 7.
// Compute identical to R6 (JW=16, sc1 state traffic, DPP weight sharing,
// pk-fma, reduce-scatter). ONLY the barrier changed: R2..R6 had every block
// polling with a full 64-lane wave on 16 shared counter lines (~16K MALL
// requests/round -> the counter banks queued ~2us/round and clogged the
// fabric serving state loads). R7: arrive spread over 16 lines as before;
// ONE summer block polls them and publishes to 16 replicated release lines;
// all other blocks poll with ONE lane + s_sleep backoff.

#define TT    512
#define RDIM  1024
#define EDIM  256
#define NL    4
#define BB    32
#define NBLK  256          // 64 blocks per layer
#define JW    16           // output columns per block
#define HDIM  (RDIM * NL)  // 4096
#define NPAN  4            // 4 panels of 8 batch rows
#define CSTRIDE 32         // dwords between counter words (128B lines)

#define S_ELEMS   (2 * NL * NPAN * RDIM * 8)   // 2 parities, 1MB
#define FIN_ELEMS (BB * HDIM)

typedef float vf2 __attribute__((ext_vector_type(2)));
typedef unsigned long long ull;

__device__ __forceinline__ float2 aload2(const ull* p) {   // 8B sc1 load
    ull u = __hip_atomic_load(p, __ATOMIC_RELAXED, __HIP_MEMORY_SCOPE_AGENT);
    union { ull u; float2 f; } c; c.u = u; return c.f;
}
__device__ __forceinline__ float dpp_xor1(float x) {   // lane ^ 1
    return __int_as_float(__builtin_amdgcn_mov_dpp(__float_as_int(x), 0xB1, 0xF, 0xF, true));
}
__device__ __forceinline__ float dpp_xor2(float x) {   // lane ^ 2
    return __int_as_float(__builtin_amdgcn_mov_dpp(__float_as_int(x), 0x4E, 0xF, 0xF, true));
}

// ---------------------------------------------------------------- gather ----
// xe[t][panel][k][8b] : panel layout matching reservoir reads
__global__ void gather_kernel(const int* __restrict__ x,
                              const float* __restrict__ embed,
                              float* __restrict__ xe)
{
    __shared__ int   ids[BB];
    __shared__ float sh[BB * (EDIM + 1)];
    const int t = blockIdx.x, tid = threadIdx.x;
    if (tid < BB) ids[tid] = x[tid * TT + t];
    __syncthreads();
    for (int r = 0; r < BB; ++r)
        sh[r * (EDIM + 1) + tid] = embed[ids[r] * EDIM + tid];
    __syncthreads();
    for (int i = tid; i < NPAN * EDIM * 8; i += 256) {
        int p = i >> 11, k = (i >> 3) & (EDIM - 1), bo = i & 7;
        xe[(size_t)t * (NPAN * EDIM * 8) + i] = sh[(p * 8 + bo) * (EDIM + 1) + k];
    }
}

// ------------------------------------------------------------- reservoir ----
__global__ __launch_bounds__(256, 1) void reservoir_kernel(
    const float* __restrict__ Win0, const float* __restrict__ WinR,
    const float* __restrict__ Rst,  const float* __restrict__ xe,
    float* __restrict__ S, float* __restrict__ Fin,
    unsigned* __restrict__ cnt, unsigned* __restrict__ rel)
{
    __shared__ float Wlds[2048 * JW];       // 128 KB, row k = 16 floats
    const int tid   = threadIdx.x;
    const int blk   = blockIdx.x;
    const int layer = blk >> 6;
    const int j0    = (blk & 63) * JW;
    const int Kin   = (layer == 0) ? EDIM : RDIM;

    // rows [0,1024) = R_stack col-slice, rows [1024,1024+Kin) = Win col-slice
    for (int idx = tid; idx < (RDIM + Kin) * JW; idx += 256) {
        int k = idx >> 4, j = idx & 15;
        float wv;
        if (k < RDIM) wv = Rst[((size_t)layer * RDIM + k) * RDIM + j0 + j];
        else {
            int k2 = k - RDIM;
            wv = (layer == 0) ? Win0[(size_t)k2 * RDIM + j0 + j]
                              : WinR[((size_t)(layer - 1) * RDIM + k2) * RDIM + j0 + j];
        }
        Wlds[idx] = wv;
    }
    __syncthreads();

    const int w   = tid >> 6;   // wave -> panel (8 batch rows)
    const int lam = tid & 63;
    const int kq  = lam >> 1;   // 32-way k split within wave
    const int bh  = lam & 1;    // which float4 of the 8-wide batch row
    const int bh4 = bh * 4;

    for (int tick = 0; tick < TT + NL - 1; ++tick) {
        const int t = tick - layer;
        if (t >= 0 && t < TT) {
            const int cur = tick & 1, prv = (tick - 1) & 1;
            const ull* ownp = (const ull*)(S + (((size_t)(prv * NL + layer)) * NPAN + w) * RDIM * 8);
            const ull* inps = (const ull*)(S + (((size_t)(prv * NL + layer - 1)) * NPAN + w) * RDIM * 8);
            const float4* inpx = (const float4*)(xe + ((size_t)t * NPAN + w) * (EDIM * 8));

            vf2 acc[4][8];
            #pragma unroll
            for (int i = 0; i < 4; ++i)
                #pragma unroll
                for (int jp = 0; jp < 8; ++jp) acc[i][jp] = (vf2)(0.f);

            // ---- own state @ R_stack (sc1 loads: coherent, no fences) ----
            #pragma unroll 8
            for (int kk = 0; kk < RDIM / 32; ++kk) {
                const ull* p = ownp + (size_t)kk * 128 + lam * 2;   // 1KB/wave
                float2 v0 = aload2(p), v1 = aload2(p + 1);
                const int k = kk * 32 + kq;
                float4 wo0 = *(const float4*)&Wlds[k * JW + bh * 8];
                float4 wo1 = *(const float4*)&Wlds[k * JW + bh * 8 + 4];
                vf2 wv[8];
                wv[0] = (vf2){wo0.x, wo0.y}; wv[1] = (vf2){wo0.z, wo0.w};
                wv[2] = (vf2){wo1.x, wo1.y}; wv[3] = (vf2){wo1.z, wo1.w};
                wv[4] = (vf2){dpp_xor1(wo0.x), dpp_xor1(wo0.y)};
                wv[5] = (vf2){dpp_xor1(wo0.z), dpp_xor1(wo0.w)};
                wv[6] = (vf2){dpp_xor1(wo1.x), dpp_xor1(wo1.y)};
                wv[7] = (vf2){dpp_xor1(wo1.z), dpp_xor1(wo1.w)};
                const float vv[4] = {v0.x, v0.y, v1.x, v1.y};
                #pragma unroll
                for (int i = 0; i < 4; ++i) {
                    vf2 s = {vv[i], vv[i]};
                    #pragma unroll
                    for (int jp = 0; jp < 8; ++jp) acc[i][jp] += s * wv[jp];
                }
            }
            // ---- layer input @ Win ----
            #pragma unroll 8
            for (int kk = 0; kk < Kin / 32; ++kk) {
                float2 v0, v1;
                if (layer == 0) {                       // xe: read-only, cached
                    float4 v = inpx[(size_t)kk * 64 + lam];
                    v0 = (float2){v.x, v.y}; v1 = (float2){v.z, v.w};
                } else {                                // state: sc1
                    const ull* p = inps + (size_t)kk * 128 + lam * 2;
                    v0 = aload2(p); v1 = aload2(p + 1);
                }
                const int k = RDIM + kk * 32 + kq;
                float4 wo0 = *(const float4*)&Wlds[k * JW + bh * 8];
                float4 wo1 = *(const float4*)&Wlds[k * JW + bh * 8 + 4];
                vf2 wv[8];
                wv[0] = (vf2){wo0.x, wo0.y}; wv[1] = (vf2){wo0.z, wo0.w};
                wv[2] = (vf2){wo1.x, wo1.y}; wv[3] = (vf2){wo1.z, wo1.w};
                wv[4] = (vf2){dpp_xor1(wo0.x), dpp_xor1(wo0.y)};
                wv[5] = (vf2){dpp_xor1(wo0.z), dpp_xor1(wo0.w)};
                wv[6] = (vf2){dpp_xor1(wo1.x), dpp_xor1(wo1.y)};
                wv[7] = (vf2){dpp_xor1(wo1.z), dpp_xor1(wo1.w)};
                const float vv[4] = {v0.x, v0.y, v1.x, v1.y};
                #pragma unroll
                for (int i = 0; i < 4; ++i) {
                    vf2 s = {vv[i], vv[i]};
                    #pragma unroll
                    for (int jp = 0; jp < 8; ++jp) acc[i][jp] += s * wv[jp];
                }
            }

            // ---- reduce-scatter over kq: 64 accs -> 2 finals per lane ----
            float r64v[64];
            #pragma unroll
            for (int i = 0; i < 4; ++i)
                #pragma unroll
                for (int jp = 0; jp < 8; ++jp) {
                    r64v[(i << 4) | (jp << 1)]     = acc[i][jp].x;
                    r64v[(i << 4) | (jp << 1) | 1] = acc[i][jp].y;
                }
            float r32v[32], r16v[16], r8v[8], r4v[4], rfin[2];
            {   const bool myb = kq & 1;                 // stage 0: DPP xor2
                #pragma unroll
                for (int m = 0; m < 32; ++m) {
                    float a = r64v[2 * m], b = r64v[2 * m + 1];
                    float send = myb ? a : b, keep = myb ? b : a;
                    r32v[m] = keep + dpp_xor2(send);
                }
            }
            {   const bool myb = (kq >> 1) & 1;          // stage 1: xor 4
                #pragma unroll
                for (int m = 0; m < 16; ++m) {
                    float a = r32v[2 * m], b = r32v[2 * m + 1];
                    float send = myb ? a : b, keep = myb ? b : a;
                    r16v[m] = keep + __shfl_xor(send, 4, 64);
                }
            }
            {   const bool myb = (kq >> 2) & 1;          // stage 2: xor 8
                #pragma unroll
                for (int m = 0; m < 8; ++m) {
                    float a = r16v[2 * m], b = r16v[2 * m + 1];
                    float send = myb ? a : b, keep = myb ? b : a;
                    r8v[m] = keep + __shfl_xor(send, 8, 64);
                }
            }
            {   const bool myb = (kq >> 3) & 1;          // stage 3: xor 16
                #pragma unroll
                for (int m = 0; m < 4; ++m) {
                    float a = r8v[2 * m], b = r8v[2 * m + 1];
                    float send = myb ? a : b, keep = myb ? b : a;
                    r4v[m] = keep + __shfl_xor(send, 16, 64);
                }
            }
            {   const bool myb = (kq >> 4) & 1;          // stage 4: xor 32
                #pragma unroll
                for (int m = 0; m < 2; ++m) {
                    float a = r4v[2 * m], b = r4v[2 * m + 1];
                    float send = myb ? a : b, keep = myb ? b : a;
                    rfin[m] = keep + __shfl_xor(send, 32, 64);
                }
            }

            // ---- epilogue: 2 outputs per lane ----
            const int i0 = kq >> 4;                 // 0..1
            const int cc = kq & 15;
            const int j  = (cc & 7) + 8 * (bh ^ (cc >> 3));   // logical col
            float* sbase = S + (((size_t)(cur * NL + layer)) * NPAN + w) * RDIM * 8
                             + (size_t)(j0 + j) * 8;
            #pragma unroll
            for (int m = 0; m < 2; ++m) {
                const int bi = bh4 + i0 + 2 * m;    // slot within panel's 8
                const float o = tanhf(rfin[m]);
                __hip_atomic_store(sbase + bi, o, __ATOMIC_RELAXED, __HIP_MEMORY_SCOPE_AGENT);
                if (t == TT - 1)
                    Fin[(size_t)(w * 8 + bi) * HDIM + layer * RDIM + j0 + j] = o;
            }
        }
        // ---- grid barrier v3: spread arrive, single summer, replicated
        //      release lines, 1-lane backoff polls (no poll storm) ----
        __syncthreads();                          // drains all waves' stores
        if (tid == 0)
            __hip_atomic_fetch_add(&cnt[(blk & 15) * CSTRIDE], 1u,
                                   __ATOMIC_RELAXED, __HIP_MEMORY_SCOPE_AGENT);
        const unsigned wrel = (unsigned)(tick + 1);
        if (blk == 0) {
            if (tid < 64) {                       // summer wave
                const unsigned wsum = wrel * (unsigned)NBLK;
                int guard = 0;
                for (;;) {
                    unsigned v = 0;
                    if (lam < 16)
                        v = __hip_atomic_load(&cnt[lam * CSTRIDE],
                                              __ATOMIC_RELAXED, __HIP_MEMORY_SCOPE_AGENT);
                    #pragma unroll
                    for (int m = 1; m <= 32; m <<= 1) v += __shfl_xor(v, m, 64);
                    if (v >= wsum) break;         // v is total on ALL lanes
                    __builtin_amdgcn_s_sleep(2);
                    if (++guard > (1 << 16)) break;   // safety valve
                }
                if (lam < 16)                     // publish release, 16 copies
                    __hip_atomic_store(&rel[lam * CSTRIDE], wrel,
                                       __ATOMIC_RELAXED, __HIP_MEMORY_SCOPE_AGENT);
            }
        } else {
            if (tid == 0) {                       // one poller lane per block
                int guard = 0;
                while (__hip_atomic_load(&rel[(blk & 15) * CSTRIDE],
                                         __ATOMIC_RELAXED, __HIP_MEMORY_SCOPE_AGENT) < wrel) {
                    __builtin_amdgcn_s_sleep(4);
                    if (++guard > (1 << 16)) break;   // safety valve
                }
            }
        }
        __syncthreads();
    }
}

// ------------------------------------------------------------- layernorm ----
__global__ void ln_kernel(const float* __restrict__ Fin,
                          const float* __restrict__ gamma,
                          const float* __restrict__ beta,
                          float* __restrict__ out)
{
    const int r = blockIdx.x, tid = threadIdx.x;
    const float* row = Fin + (size_t)r * HDIM;
    float s = 0.f, s2 = 0.f;
    for (int i = tid; i < HDIM; i += 256) { float v = row[i]; s += v; s2 += v * v; }
    for (int off = 32; off; off >>= 1) {
        s  += __shfl_down(s,  off, 64);
        s2 += __shfl_down(s2, off, 64);
    }
    __shared__ float rs[4], rs2[4];
    __shared__ float mu_s, rstd_s;
    if ((tid & 63) == 0) { rs[tid >> 6] = s; rs2[tid >> 6] = s2; }
    __syncthreads();
    if (tid == 0) {
        float S1 = rs[0] + rs[1] + rs[2] + rs[3];
        float S2 = rs2[0] + rs2[1] + rs2[2] + rs2[3];
        float mu = S1 / (float)HDIM;
        float var = S2 / (float)HDIM - mu * mu;
        mu_s = mu; rstd_s = rsqrtf(var + 1e-5f);
    }
    __syncthreads();
    float mu = mu_s, rstd = rstd_s;
    for (int i = tid; i < HDIM; i += 256)
        out[(size_t)r * HDIM + i] = (row[i] - mu) * rstd * gamma[i] + beta[i];
}

// ----------------------------------------------------------------- launch ---
extern "C" void kernel_launch(void* const* d_in, const int* in_sizes, int n_in,
                              void* d_out, int out_size, void* d_ws, size_t ws_size,
                              hipStream_t stream)
{
    const int*   x     = (const int*)d_in[0];
    const float* embed = (const float*)d_in[1];
    const float* Win0  = (const float*)d_in[2];
    const float* WinR  = (const float*)d_in[3];
    const float* Rst   = (const float*)d_in[4];
    const float* gamma = (const float*)d_in[5];
    const float* beta  = (const float*)d_in[6];
    float* out = (float*)d_out;

    char* ws = (char*)d_ws;
    unsigned* cnt = (unsigned*)ws;                    // 16 lines (arrive)
    unsigned* rel = cnt + 16 * CSTRIDE;               // 16 lines (release)
    float* S   = (float*)(ws + 8192);                                // 1MB
    float* Fin = S + S_ELEMS;                                        // 0.5MB
    float* xe  = Fin + FIN_ELEMS;                                    // 16.8MB

    hipMemsetAsync(ws, 0, 8192 + (size_t)S_ELEMS * 4, stream);       // flags+states
    gather_kernel   <<<TT,   256, 0, stream>>>(x, embed, xe);
    reservoir_kernel<<<NBLK, 256, 0, stream>>>(Win0, WinR, Rst, xe, S, Fin, cnt, rel);
    ln_kernel       <<<BB,   256, 0, stream>>>(Fin, gamma, beta, out);
}